// Round 4
// baseline (512.183 us; speedup 1.0000x reference)
//
#include <hip/hip_runtime.h>

namespace {

constexpr int NB = 32, NL = 1024, NC = 128, NP = 96, KW = 5;
constexpr float INV_SQRT2 = 0.70710678118654752440f;

typedef unsigned short u16;
typedef __attribute__((ext_vector_type(4))) u16 u16x4;
typedef __attribute__((ext_vector_type(8))) u16 u16x8;
typedef __attribute__((ext_vector_type(8))) short short8;
typedef __attribute__((ext_vector_type(4))) float f32x4;

__device__ inline u16 f2bf(float f) {
  unsigned u = __float_as_uint(f);
  u += 0x7fff + ((u >> 16) & 1);
  return (u16)(u >> 16);
}

__device__ inline float ftanh(float x) {
  float e = __expf(2.f * x);
  return 1.f - 2.f / (e + 1.f);
}

// ---------------- stats stage 1: per (b, L-slice) partial sums ----------------
__global__ void stats1(const float* __restrict__ x, const float* __restrict__ mask,
                       float* __restrict__ part) {
  int b = blockIdx.x, s = blockIdx.y;
  int tid = threadIdx.x;
  int c = tid & 127, lh = tid >> 7;
  const float* xb = x + (size_t)b * NL * NC;
  const float* mb = mask + (size_t)b * NL * NC;
  float s_all = 0.f, d1 = 0.f, sm = 0.f, sm2 = 0.f, cnz = 0.f;
#pragma unroll 4
  for (int i = 0; i < 32; ++i) {
    int l = s * 64 + lh + 2 * i;
    float v = xb[(size_t)l * NC + c];
    float m = mb[(size_t)l * NC + c];
    s_all += v;
    d1 += (m == 1.f) ? 1.f : 0.f;
    bool nz = (m != 0.f);
    float vm = nz ? v : 0.f;
    sm += vm;
    sm2 += vm * v;
    cnz += nz ? 1.f : 0.f;
  }
  __shared__ float red[5][256];
  red[0][tid] = s_all; red[1][tid] = d1; red[2][tid] = sm;
  red[3][tid] = sm2;   red[4][tid] = cnz;
  __syncthreads();
  if (lh == 0) {
    float* pp = part + ((size_t)(b * 16 + s) * 5) * NC + c;
#pragma unroll
    for (int q = 0; q < 5; ++q) pp[q * NC] = red[q][c] + red[q][c + 128];
  }
}

__global__ void stats2(const float* __restrict__ part, float* __restrict__ means,
                       float* __restrict__ stdev) {
  int b = blockIdx.x, c = threadIdx.x;  // 128 threads
  float s_all = 0.f, d1 = 0.f, sm = 0.f, sm2 = 0.f, cnz = 0.f;
  for (int s = 0; s < 16; ++s) {
    const float* pp = part + ((size_t)(b * 16 + s) * 5) * NC + c;
    s_all += pp[0];
    d1    += pp[NC];
    sm    += pp[2 * NC];
    sm2   += pp[3 * NC];
    cnz   += pp[4 * NC];
  }
  float mn = s_all / d1;
  float varsum = sm2 - 2.f * mn * sm + mn * mn * cnz;
  means[b * NC + c] = mn;
  stdev[b * NC + c] = sqrtf(varsum / d1 + 1e-5f);
}

// ---------------- normalize + transpose (B,L,C) -> (B,C,L) ----------------
__global__ void norm_transpose(const float* __restrict__ x, const float* __restrict__ mask,
                               const float* __restrict__ means, const float* __restrict__ stdev,
                               float* __restrict__ xt) {
  __shared__ float tile[32][33];
  int b = blockIdx.x;
  int l0 = blockIdx.y * 32;
  int c0 = blockIdx.z * 32;
  int tx = threadIdx.x;
  int ty = threadIdx.y;
  for (int i = ty; i < 32; i += 8) {
    int l = l0 + i, c = c0 + tx;
    float v = x[((size_t)b * NL + l) * NC + c];
    float m = mask[((size_t)b * NL + l) * NC + c];
    float val = (m == 0.f) ? 0.f : (v - means[b * NC + c]);
    tile[i][tx] = val / stdev[b * NC + c];
  }
  __syncthreads();
  for (int i = ty; i < 32; i += 8) {
    xt[((size_t)b * NC + c0 + i) * NL + l0 + tx] = tile[tx][i];
  }
}

// ---------------- Haar transform per row (length 1024), bf16 out ----------------
__global__ void haar_kernel(const float* __restrict__ xt, u16* __restrict__ freqb) {
  int row = blockIdx.x;
  __shared__ float h[1024], t2[512];
  const float* src = xt + (size_t)row * NL;
  u16* dst = freqb + (size_t)row * NL;
  for (int i = threadIdx.x; i < 1024; i += 256) h[i] = src[i];
  __syncthreads();
  int n = 1024;
  while (n > 1) {
    int half = n >> 1;
    for (int i = threadIdx.x; i < half; i += 256) {
      float e = h[2 * i], o = h[2 * i + 1];
      dst[half + i] = f2bf((e - o) * INV_SQRT2);
      t2[i] = (e + o) * INV_SQRT2;
    }
    __syncthreads();
    for (int i = threadIdx.x; i < half; i += 256) h[i] = t2[i];
    __syncthreads();
    n = half;
  }
  if (threadIdx.x == 0) dst[0] = f2bf(h[0]);
}

// ---------------- f32 -> bf16 convert (n multiple of 4) ----------------
__global__ void cvt_bf16(const float* __restrict__ in, u16* __restrict__ outp, int n4) {
  int i = blockIdx.x * 256 + threadIdx.x;
  if (i < n4) {
    const float4 v = *reinterpret_cast<const float4*>(in + (size_t)i * 4);
    u16x4 o;
    o.x = f2bf(v.x); o.y = f2bf(v.y); o.z = f2bf(v.z); o.w = f2bf(v.w);
    *reinterpret_cast<u16x4*>(outp + (size_t)i * 4) = o;
  }
}

// ---------------- pack conv weights [60][co][ci][k] f32 -> [60][k][co][ci] bf16 ----------------
// thread = (n,co,ci): reads 5 consecutive floats, writes 5 coalesced bf16 planes
__global__ void pack_w(const float* __restrict__ w, u16* __restrict__ wp) {
  int idx = blockIdx.x * 256 + threadIdx.x;  // over 60*128*128
  if (idx >= 60 * 128 * 128) return;
  int ci = idx & 127;
  int co = (idx >> 7) & 127;
  int n = idx >> 14;
  const float* src = w + (size_t)idx * 5;
  size_t base = (size_t)n * (5 * 128 * 128) + (size_t)co * 128 + ci;
#pragma unroll
  for (int k = 0; k < 5; ++k)
    wp[base + (size_t)k * 16384] = f2bf(src[k]);
}

// ---------------- bf16 MFMA GEMM NT, tile 128m x 64n x 64k ----------------
// EPI 0: relu -> bf16 out; EPI 1: sigmoid -> f32 out
template <int EPI>
__global__ __launch_bounds__(256) void gemm_mfma(const u16* __restrict__ A,
                                                 const u16* __restrict__ Bw,
                                                 u16* __restrict__ Cb, float* __restrict__ Cf,
                                                 int M, int N, int K) {
  __shared__ __align__(16) char sAB[(128 + 64) * 128];  // A rows 0..127, B rows 128..191
  int m0 = blockIdx.y * 128, n0 = blockIdx.x * 64;
  int tid = threadIdx.x;
  int lane = tid & 63, wv = tid >> 6;
  int wm = (wv >> 1) * 64, wn = (wv & 1) * 32;
  int lg = lane >> 4, l15 = lane & 15;
  f32x4 zero = {0.f, 0.f, 0.f, 0.f};
  f32x4 acc[4][2];
#pragma unroll
  for (int i = 0; i < 4; ++i)
#pragma unroll
    for (int j = 0; j < 2; ++j) acc[i][j] = zero;

  for (int k0 = 0; k0 < K; k0 += 64) {
    __syncthreads();
#pragma unroll
    for (int pass = 0; pass < 6; ++pass) {
      int o = pass * 4096 + tid * 16;
      int cb = o & 127;
      int row;
      const u16* srcp;
      if (pass < 4) {
        row = o >> 7;
        srcp = A + (size_t)(m0 + row) * K + k0 + (cb >> 1);
      } else {
        int rb = (o - 16384) >> 7;
        row = 128 + rb;
        srcp = Bw + (size_t)(n0 + rb) * K + k0 + (cb >> 1);
      }
      int sw = row * 128 + (cb ^ ((row & 7) << 4));
      *(u16x8*)(sAB + sw) = *(const u16x8*)srcp;
    }
    __syncthreads();
#pragma unroll
    for (int ks = 0; ks < 2; ++ks) {
      int kb = ks * 64 + lg * 16;
      short8 a[4], bbf[2];
#pragma unroll
      for (int mt = 0; mt < 4; ++mt) {
        int rr = wm + mt * 16 + l15;
        a[mt] = *(const short8*)(sAB + rr * 128 + (kb ^ ((rr & 7) << 4)));
      }
#pragma unroll
      for (int nt = 0; nt < 2; ++nt) {
        int rr = 128 + wn + nt * 16 + l15;
        bbf[nt] = *(const short8*)(sAB + rr * 128 + (kb ^ ((rr & 7) << 4)));
      }
#pragma unroll
      for (int mt = 0; mt < 4; ++mt)
#pragma unroll
        for (int nt = 0; nt < 2; ++nt)
          acc[mt][nt] = __builtin_amdgcn_mfma_f32_16x16x32_bf16(a[mt], bbf[nt], acc[mt][nt], 0, 0, 0);
    }
  }
#pragma unroll
  for (int mt = 0; mt < 4; ++mt)
#pragma unroll
    for (int nt = 0; nt < 2; ++nt)
#pragma unroll
      for (int r = 0; r < 4; ++r) {
        int row = m0 + wm + mt * 16 + lg * 4 + r;
        int col = n0 + wn + nt * 16 + l15;
        float v = acc[mt][nt][r];
        if (EPI == 0) {
          v = v > 0.f ? v : 0.f;
          Cb[(size_t)row * N + col] = f2bf(v);
        } else {
          Cf[(size_t)row * N + col] = 1.f / (1.f + __expf(-v));
        }
      }
}

// ---------------- LayerNorm over last dim (1024) per row, in place ----------------
__global__ void ln_kernel(float* __restrict__ lr, const float* __restrict__ g,
                          const float* __restrict__ bta) {
  int row = blockIdx.x;
  float* p = lr + (size_t)row * 1024;
  int tid = threadIdx.x;
  float v[4];
#pragma unroll
  for (int i = 0; i < 4; ++i) v[i] = p[tid + 256 * i];
  __shared__ float red[256];
  red[tid] = v[0] + v[1] + v[2] + v[3];
  __syncthreads();
  for (int off = 128; off > 0; off >>= 1) {
    if (tid < off) red[tid] += red[tid + off];
    __syncthreads();
  }
  float mu = red[0] * (1.f / 1024.f);
  __syncthreads();
  float sq = 0.f;
#pragma unroll
  for (int i = 0; i < 4; ++i) { float d = v[i] - mu; sq += d * d; }
  red[tid] = sq;
  __syncthreads();
  for (int off = 128; off > 0; off >>= 1) {
    if (tid < off) red[tid] += red[tid + off];
    __syncthreads();
  }
  float rs = rsqrtf(red[0] * (1.f / 1024.f) + 1e-6f);
#pragma unroll
  for (int i = 0; i < 4; ++i) {
    int idx = tid + 256 * i;
    p[idx] = (v[i] - mu) * rs * g[idx] + bta[idx];
  }
}

// ---------------- x_t = x_t * lr + pe (pe computed inline) ----------------
__global__ void combine_kernel(float* __restrict__ xt, const float* __restrict__ lr) {
  size_t idx = (size_t)blockIdx.x * 256 + threadIdx.x;
  int l = (int)(idx & 1023);
  int c = (int)((idx >> 10) & 127);
  int t = c & 63;
  float inv = __expf(-0.14619589f * (float)t);  // log(10000)/63
  float st = (float)l * inv;
  float pe = (c < 64) ? sinf(st) : cosf(st);
  xt[idx] = xt[idx] * lr[idx] + pe;
}

// ---------------- fused CIL half-node: MFMA conv1+leaky+conv2+tanh+combine ----------------
constexpr size_t SEGc = (size_t)NB * NC;
constexpr size_t XOT = 2097152;  // element offset of xot within xet buffer
constexpr int TT = 32;           // conv2 outputs per block
constexpr int RIN = 56;          // staged input rows, i <-> x[t0-4+i], need i<52

template <int PHASE, int LEAF>
__global__ __launch_bounds__(256, 4) void ccb_mfma(const float* __restrict__ src,
                                                   float* __restrict__ dst,
                                                   const u16* __restrict__ wp1,
                                                   const u16* __restrict__ wp2,
                                                   const float* __restrict__ b1,
                                                   const float* __restrict__ b2,
                                                   int d, int Tn) {
  __shared__ __align__(16) char lds[RIN * 256];          // in tile -> mid tile, XOR swizzled
  __shared__ float oth_s[PHASE == 0 ? (TT * 130) : 4];   // phase0: other-parity fp32 tile
  int b = blockIdx.x;
  int t0 = blockIdx.y * TT;
  int z = blockIdx.z;
  int p = z >> 1, br = z & 1;
  // preorder node index of (depth d, BFS pos p)
  int node = 0;
  for (int i2 = d - 1; i2 >= 0; --i2) {
    int bit = (p >> i2) & 1;
    int dd = d - 1 - i2;
    node += 1 + bit * ((1 << (3 - dd)) - 1);
  }
  int widx = node * 4 + PHASE * 2 + br;
  const u16* W1 = wp1 + (size_t)widx * (5 * 128 * 128);
  const u16* W2 = wp2 + (size_t)widx * (5 * 128 * 128);
  const float* B1 = b1 + (size_t)widx * 128;
  const float* B2 = b2 + (size_t)widx * 128;

  const float* inp;
  const float* oth = nullptr;
  float* outp;
  int dts;
  size_t irow, orow = 0, drow;
  if (PHASE == 0) {
    inp = src + (size_t)p * SEGc * (size_t)(2 * Tn);   // parent, e/o interleaved along t
    irow = (size_t)(2 * Tn);
    outp = dst + (br ? XOT : 0) + (size_t)p * SEGc * Tn;
    dts = 1; drow = (size_t)Tn;
  } else {
    inp = src + (br ? 0 : XOT) + (size_t)p * SEGc * Tn;  // br0: xot; br1: xet
    oth = src + (br ? XOT : 0) + (size_t)p * SEGc * Tn;
    irow = (size_t)Tn;
    orow = (size_t)Tn;
    if (!LEAF) {
      outp = dst + (size_t)(2 * p + br) * SEGc * Tn;
      dts = 1; drow = (size_t)Tn;
    } else {
      int rev = ((p & 1) << 2) | (p & 2) | ((p >> 2) & 1);
      outp = dst + rev + br * 8;
      dts = 16; drow = (size_t)NL;
    }
  }

  int tid = threadIdx.x;
  const float* inb = inp + (size_t)b * NC * irow;
  // ---- stage: in -> bf16 tile [i][ci] swizzled; phase0 also oth -> fp32 LDS ----
  {
    int i = tid & 63;        // row (= lane)
    int prb = tid >> 6;      // wave id
    if (i < RIN) {
      int t = t0 - 4 + i;
      t = t < 0 ? 0 : (t >= Tn ? Tn - 1 : t);
      bool orow_ok = (i >= 4) && (i < 4 + TT);
#pragma unroll
      for (int pp = 0; pp < 16; ++pp) {
        int pr = prb + 4 * pp;   // ci pair
        float in0, in1;
        if (PHASE == 0) {
          float2 v0 = *(const float2*)(inb + (size_t)(2 * pr) * irow + 2 * t);
          float2 v1 = *(const float2*)(inb + (size_t)(2 * pr + 1) * irow + 2 * t);
          float ot0, ot1;
          if (br) { in0 = v0.x; ot0 = v0.y; in1 = v1.x; ot1 = v1.y; }
          else    { in0 = v0.y; ot0 = v0.x; in1 = v1.y; ot1 = v1.x; }
          if (orow_ok) *(float2*)(&oth_s[(i - 4) * 130 + 2 * pr]) = make_float2(ot0, ot1);
        } else {
          in0 = inb[(size_t)(2 * pr) * irow + t];
          in1 = inb[(size_t)(2 * pr + 1) * irow + t];
        }
        unsigned pk = (unsigned)f2bf(in0) | ((unsigned)f2bf(in1) << 16);
        *(unsigned*)(lds + i * 256 + ((4 * pr) ^ ((i & 15) << 4))) = pk;
      }
    }
  }
  __syncthreads();

  int lane = tid & 63, wv = tid >> 6;
  int lg = lane >> 4, l15 = lane & 15;

  // ---- conv1: mid[j] = leaky(sum_{ci,k} x[j+k] w1[k]), j in [0,48) ----
  f32x4 acc1[2][3];
#pragma unroll
  for (int mt = 0; mt < 2; ++mt) {
    const f32x4 bv = *(const f32x4*)(B1 + wv * 32 + mt * 16 + lg * 4);
#pragma unroll
    for (int nt = 0; nt < 3; ++nt) acc1[mt][nt] = bv;
  }
  for (int k = 0; k < 5; ++k) {
#pragma unroll
    for (int cig = 0; cig < 4; ++cig) {
      int ci0 = cig * 32 + lg * 8;
      short8 a[2], bb[3];
#pragma unroll
      for (int mt = 0; mt < 2; ++mt) {
        int co = wv * 32 + mt * 16 + l15;
        a[mt] = *(const short8*)(W1 + ((size_t)(k * 128 + co) * 128 + ci0));
      }
      int cbyte = 2 * ci0;
#pragma unroll
      for (int nt = 0; nt < 3; ++nt) {
        int i = nt * 16 + l15 + k;   // <= 51
        bb[nt] = *(const short8*)(lds + i * 256 + (cbyte ^ ((i & 15) << 4)));
      }
#pragma unroll
      for (int mt = 0; mt < 2; ++mt)
#pragma unroll
        for (int nt = 0; nt < 3; ++nt)
          acc1[mt][nt] = __builtin_amdgcn_mfma_f32_16x16x32_bf16(a[mt], bb[nt], acc1[mt][nt], 0, 0, 0);
    }
  }
  __syncthreads();  // conv1 LDS reads complete before overwrite

  // ---- leaky relu -> mid tile (same buffer, same swizzle) ----
#pragma unroll
  for (int mt = 0; mt < 2; ++mt)
#pragma unroll
    for (int nt = 0; nt < 3; ++nt) {
      int j = nt * 16 + l15;
      int co0 = wv * 32 + mt * 16 + lg * 4;
      u16x4 m;
#pragma unroll
      for (int r = 0; r < 4; ++r) {
        float v = acc1[mt][nt][r];
        v = v > 0.f ? v : 0.01f * v;
        m[r] = f2bf(v);
      }
      *(u16x4*)(lds + j * 256 + ((2 * co0) ^ ((j & 15) << 4))) = m;
    }
  __syncthreads();

  // ---- conv2: z[t] = sum_{ci,k} mid[t+k][ci] w2[k][co][ci], t in [0,32) ----
  f32x4 acc2[2][2];
#pragma unroll
  for (int mt = 0; mt < 2; ++mt) {
    const f32x4 bv = *(const f32x4*)(B2 + wv * 32 + mt * 16 + lg * 4);
#pragma unroll
    for (int nt = 0; nt < 2; ++nt) acc2[mt][nt] = bv;
  }
  for (int k = 0; k < 5; ++k) {
#pragma unroll
    for (int cig = 0; cig < 4; ++cig) {
      int ci0 = cig * 32 + lg * 8;
      short8 a[2], bb[2];
#pragma unroll
      for (int mt = 0; mt < 2; ++mt) {
        int co = wv * 32 + mt * 16 + l15;
        a[mt] = *(const short8*)(W2 + ((size_t)(k * 128 + co) * 128 + ci0));
      }
      int cbyte = 2 * ci0;
#pragma unroll
      for (int nt = 0; nt < 2; ++nt) {
        int i = nt * 16 + l15 + k;   // <= 35
        bb[nt] = *(const short8*)(lds + i * 256 + (cbyte ^ ((i & 15) << 4)));
      }
#pragma unroll
      for (int mt = 0; mt < 2; ++mt)
#pragma unroll
        for (int nt = 0; nt < 2; ++nt)
          acc2[mt][nt] = __builtin_amdgcn_mfma_f32_16x16x32_bf16(a[mt], bb[nt], acc2[mt][nt], 0, 0, 0);
    }
  }

  // ---- tanh + combine + store ----
  float* outb = outp + (size_t)b * NC * drow;
  const float* othb = (PHASE == 1) ? (oth + (size_t)b * NC * orow) : nullptr;
#pragma unroll
  for (int mt = 0; mt < 2; ++mt)
#pragma unroll
    for (int nt = 0; nt < 2; ++nt) {
      int tl = nt * 16 + l15;
      int t = t0 + tl;
#pragma unroll
      for (int r = 0; r < 4; ++r) {
        int co = wv * 32 + mt * 16 + lg * 4 + r;
        float cv = ftanh(acc2[mt][nt][r]);
        float ov = (PHASE == 0) ? oth_s[tl * 130 + co]
                                : othb[(size_t)co * orow + t];
        float res;
        if (PHASE == 0) res = ov * __expf(cv);
        else            res = (br == 0) ? ov + cv : ov - cv;
        outb[(size_t)co * drow + (size_t)t * dts] = res;
      }
    }
}

// ---------------- final projection + denorm ----------------
__global__ void final_kernel(const float* __restrict__ dect, const float* __restrict__ xt,
                             const float* __restrict__ projw, const float* __restrict__ means,
                             const float* __restrict__ stdev, float* __restrict__ out) {
  int b = blockIdx.x, p = blockIdx.y;
  int tid = threadIdx.x;
  const float* w = projw + (size_t)(1024 + p) * 1024;
  const float* d0 = dect + (size_t)b * NC * NL;
  const float* x0 = xt + (size_t)b * NC * NL;
  float a[3] = {0.f, 0.f, 0.f};
  for (int l = tid; l < 1024; l += 256) {
    float wv = w[l];
#pragma unroll
    for (int cc = 0; cc < 3; ++cc)
      a[cc] += wv * (d0[(size_t)cc * NL + l] + x0[(size_t)cc * NL + l]);
  }
  __shared__ float red[3][256];
  for (int cc = 0; cc < 3; ++cc) red[cc][tid] = a[cc];
  __syncthreads();
  for (int off = 128; off > 0; off >>= 1) {
    if (tid < off) {
      red[0][tid] += red[0][tid + off];
      red[1][tid] += red[1][tid + off];
      red[2][tid] += red[2][tid + off];
    }
    __syncthreads();
  }
  if (tid < 3) {
    out[((size_t)b * NP + p) * 3 + tid] = red[tid][0] * stdev[b * NC + tid] + means[b * NC + tid];
  }
}

}  // namespace

extern "C" void kernel_launch(void* const* d_in, const int* in_sizes, int n_in,
                              void* d_out, int out_size, void* d_ws, size_t ws_size,
                              hipStream_t stream) {
  (void)in_sizes; (void)n_in; (void)out_size; (void)ws_size;
  const float* x_enc = (const float*)d_in[0];
  const float* mask  = (const float*)d_in[1];
  const float* fc1_w = (const float*)d_in[2];
  const float* fc2_w = (const float*)d_in[3];
  const float* ln_g  = (const float*)d_in[4];
  const float* ln_b  = (const float*)d_in[5];
  const float* w1    = (const float*)d_in[6];
  const float* b1    = (const float*)d_in[7];
  const float* w2    = (const float*)d_in[8];
  const float* b2    = (const float*)d_in[9];
  const float* projw = (const float*)d_in[10];
  float* out = (float*)d_out;
  float* ws = (float*)d_ws;

  // workspace layout (floats)
  float* means = ws + 0;          // 4096
  float* stdev = ws + 4096;       // 4096
  float* x_t   = ws + 139264;     // 4,194,304  (B,C,L) fp32, depth-0 buf
  float* freq  = ws + 4333568;    // 4,194,304  lr fp32 -> IN3 (depth-3 buf)
  float* IN1   = ws + 8527872;    // 4,194,304  hid_bf (bf16) -> depth-1 buf
  float* IN2   = ws + 12722176;   // 4,194,304  fc w bf16 -> depth-2 buf -> dect
  float* xet   = ws + 16916480;   // 2,097,152  freq_bf (bf16) alias -> xet
  float* wp1f  = ws + 21110784;   // stats partials (early) -> packed conv w1 bf16
  float* wp2f  = ws + 23568384;   // packed conv w2 bf16
  float* dect = IN2;
  float* stats_part = wp1f;
  u16* freq_bf = (u16*)xet;
  u16* hid_bf  = (u16*)IN1;
  u16* fc1w_bf = (u16*)IN2;
  u16* fc2w_bf = (u16*)(IN2 + 1048576);
  u16* wp1 = (u16*)wp1f;
  u16* wp2 = (u16*)wp2f;

  stats1<<<dim3(NB, 16), 256, 0, stream>>>(x_enc, mask, stats_part);
  stats2<<<NB, 128, 0, stream>>>(stats_part, means, stdev);
  norm_transpose<<<dim3(NB, NL / 32, NC / 32), dim3(32, 8), 0, stream>>>(x_enc, mask, means, stdev, x_t);
  haar_kernel<<<NB * NC, 256, 0, stream>>>(x_t, freq_bf);

  cvt_bf16<<<2048, 256, 0, stream>>>(fc1_w, fc1w_bf, 524288);
  cvt_bf16<<<2048, 256, 0, stream>>>(fc2_w, fc2w_bf, 524288);
  pack_w<<<3840, 256, 0, stream>>>(w1, wp1);
  pack_w<<<3840, 256, 0, stream>>>(w2, wp2);

  gemm_mfma<0><<<dim3(32, 32), 256, 0, stream>>>(freq_bf, fc1w_bf, hid_bf, nullptr, 4096, 2048, 1024);
  gemm_mfma<1><<<dim3(16, 32), 256, 0, stream>>>(hid_bf, fc2w_bf, nullptr, freq, 4096, 1024, 2048);

  ln_kernel<<<4096, 256, 0, stream>>>(freq, ln_g, ln_b);
  combine_kernel<<<(NB * NC * NL) / 256, 256, 0, stream>>>(x_t, freq);

  float* depthbuf[4] = {x_t, IN1, IN2, freq};
  for (int d = 0; d < 4; ++d) {
    int Tn = 512 >> d;
    int nsub = 1 << d;
    dim3 grid(NB, Tn / TT, 2 * nsub);
    ccb_mfma<0, 0><<<grid, 256, 0, stream>>>(depthbuf[d], xet, wp1, wp2, b1, b2, d, Tn);
    if (d < 3) {
      ccb_mfma<1, 0><<<grid, 256, 0, stream>>>(xet, depthbuf[d + 1], wp1, wp2, b1, b2, d, Tn);
    } else {
      ccb_mfma<1, 1><<<grid, 256, 0, stream>>>(xet, dect, wp1, wp2, b1, b2, d, Tn);
    }
  }

  final_kernel<<<dim3(NB, NP), 256, 0, stream>>>(dect, x_t, projw, means, stdev, out);
}

// Round 5
// 479.937 us; speedup vs baseline: 1.0672x; 1.0672x over previous
//
#include <hip/hip_runtime.h>

namespace {

constexpr int NB = 32, NL = 1024, NC = 128, NP = 96, KW = 5;
constexpr float INV_SQRT2 = 0.70710678118654752440f;

typedef unsigned short u16;
typedef __attribute__((ext_vector_type(4))) u16 u16x4;
typedef __attribute__((ext_vector_type(8))) u16 u16x8;
typedef __attribute__((ext_vector_type(8))) short short8;
typedef __attribute__((ext_vector_type(4))) float f32x4;

__device__ inline u16 f2bf(float f) {
  unsigned u = __float_as_uint(f);
  u += 0x7fff + ((u >> 16) & 1);
  return (u16)(u >> 16);
}

__device__ inline float ftanh(float x) {
  float e = __expf(2.f * x);
  return 1.f - 2.f / (e + 1.f);
}

// ---------------- stats stage 1 ----------------
__global__ void stats1(const float* __restrict__ x, const float* __restrict__ mask,
                       float* __restrict__ part) {
  int b = blockIdx.x, s = blockIdx.y;
  int tid = threadIdx.x;
  int c = tid & 127, lh = tid >> 7;
  const float* xb = x + (size_t)b * NL * NC;
  const float* mb = mask + (size_t)b * NL * NC;
  float s_all = 0.f, d1 = 0.f, sm = 0.f, sm2 = 0.f, cnz = 0.f;
#pragma unroll 4
  for (int i = 0; i < 32; ++i) {
    int l = s * 64 + lh + 2 * i;
    float v = xb[(size_t)l * NC + c];
    float m = mb[(size_t)l * NC + c];
    s_all += v;
    d1 += (m == 1.f) ? 1.f : 0.f;
    bool nz = (m != 0.f);
    float vm = nz ? v : 0.f;
    sm += vm;
    sm2 += vm * v;
    cnz += nz ? 1.f : 0.f;
  }
  __shared__ float red[5][256];
  red[0][tid] = s_all; red[1][tid] = d1; red[2][tid] = sm;
  red[3][tid] = sm2;   red[4][tid] = cnz;
  __syncthreads();
  if (lh == 0) {
    float* pp = part + ((size_t)(b * 16 + s) * 5) * NC + c;
#pragma unroll
    for (int q = 0; q < 5; ++q) pp[q * NC] = red[q][c] + red[q][c + 128];
  }
}

__global__ void stats2(const float* __restrict__ part, float* __restrict__ means,
                       float* __restrict__ stdev) {
  int b = blockIdx.x, c = threadIdx.x;
  float s_all = 0.f, d1 = 0.f, sm = 0.f, sm2 = 0.f, cnz = 0.f;
  for (int s = 0; s < 16; ++s) {
    const float* pp = part + ((size_t)(b * 16 + s) * 5) * NC + c;
    s_all += pp[0];
    d1    += pp[NC];
    sm    += pp[2 * NC];
    sm2   += pp[3 * NC];
    cnz   += pp[4 * NC];
  }
  float mn = s_all / d1;
  float varsum = sm2 - 2.f * mn * sm + mn * mn * cnz;
  means[b * NC + c] = mn;
  stdev[b * NC + c] = sqrtf(varsum / d1 + 1e-5f);
}

// ---------------- normalize + transpose (B,L,C) -> (B,C,L) ----------------
__global__ void norm_transpose(const float* __restrict__ x, const float* __restrict__ mask,
                               const float* __restrict__ means, const float* __restrict__ stdev,
                               float* __restrict__ xt) {
  __shared__ float tile[32][33];
  int b = blockIdx.x;
  int l0 = blockIdx.y * 32;
  int c0 = blockIdx.z * 32;
  int tx = threadIdx.x;
  int ty = threadIdx.y;
  for (int i = ty; i < 32; i += 8) {
    int l = l0 + i, c = c0 + tx;
    float v = x[((size_t)b * NL + l) * NC + c];
    float m = mask[((size_t)b * NL + l) * NC + c];
    float val = (m == 0.f) ? 0.f : (v - means[b * NC + c]);
    tile[i][tx] = val / stdev[b * NC + c];
  }
  __syncthreads();
  for (int i = ty; i < 32; i += 8) {
    xt[((size_t)b * NC + c0 + i) * NL + l0 + tx] = tile[tx][i];
  }
}

// ---------------- Haar transform per row, bf16 out ----------------
__global__ void haar_kernel(const float* __restrict__ xt, u16* __restrict__ freqb) {
  int row = blockIdx.x;
  __shared__ float h[1024], t2[512];
  const float* src = xt + (size_t)row * NL;
  u16* dst = freqb + (size_t)row * NL;
  for (int i = threadIdx.x; i < 1024; i += 256) h[i] = src[i];
  __syncthreads();
  int n = 1024;
  while (n > 1) {
    int half = n >> 1;
    for (int i = threadIdx.x; i < half; i += 256) {
      float e = h[2 * i], o = h[2 * i + 1];
      dst[half + i] = f2bf((e - o) * INV_SQRT2);
      t2[i] = (e + o) * INV_SQRT2;
    }
    __syncthreads();
    for (int i = threadIdx.x; i < half; i += 256) h[i] = t2[i];
    __syncthreads();
    n = half;
  }
  if (threadIdx.x == 0) dst[0] = f2bf(h[0]);
}

// ---------------- f32 -> bf16 ----------------
__global__ void cvt_bf16(const float* __restrict__ in, u16* __restrict__ outp, int n4) {
  int i = blockIdx.x * 256 + threadIdx.x;
  if (i < n4) {
    const float4 v = *reinterpret_cast<const float4*>(in + (size_t)i * 4);
    u16x4 o;
    o.x = f2bf(v.x); o.y = f2bf(v.y); o.z = f2bf(v.z); o.w = f2bf(v.w);
    *reinterpret_cast<u16x4*>(outp + (size_t)i * 4) = o;
  }
}

// ---------------- pack conv weights [60][co][ci][k] -> [60][k][co][ci] bf16 ----------------
__global__ void pack_w(const float* __restrict__ w, u16* __restrict__ wp) {
  int idx = blockIdx.x * 256 + threadIdx.x;
  if (idx >= 60 * 128 * 128) return;
  int ci = idx & 127;
  int co = (idx >> 7) & 127;
  int n = idx >> 14;
  const float* src = w + (size_t)idx * 5;
  size_t base = (size_t)n * (5 * 128 * 128) + (size_t)co * 128 + ci;
#pragma unroll
  for (int k = 0; k < 5; ++k)
    wp[base + (size_t)k * 16384] = f2bf(src[k]);
}

// ---------------- bf16 MFMA GEMM NT, tile 128m x 64n x 64k ----------------
template <int EPI>
__global__ __launch_bounds__(256) void gemm_mfma(const u16* __restrict__ A,
                                                 const u16* __restrict__ Bw,
                                                 u16* __restrict__ Cb, float* __restrict__ Cf,
                                                 int M, int N, int K) {
  __shared__ __align__(16) char sAB[(128 + 64) * 128];
  int m0 = blockIdx.y * 128, n0 = blockIdx.x * 64;
  int tid = threadIdx.x;
  int lane = tid & 63, wv = tid >> 6;
  int wm = (wv >> 1) * 64, wn = (wv & 1) * 32;
  int lg = lane >> 4, l15 = lane & 15;
  f32x4 zero = {0.f, 0.f, 0.f, 0.f};
  f32x4 acc[4][2];
#pragma unroll
  for (int i = 0; i < 4; ++i)
#pragma unroll
    for (int j = 0; j < 2; ++j) acc[i][j] = zero;

  for (int k0 = 0; k0 < K; k0 += 64) {
    __syncthreads();
#pragma unroll
    for (int pass = 0; pass < 6; ++pass) {
      int o = pass * 4096 + tid * 16;
      int cb = o & 127;
      int row;
      const u16* srcp;
      if (pass < 4) {
        row = o >> 7;
        srcp = A + (size_t)(m0 + row) * K + k0 + (cb >> 1);
      } else {
        int rb = (o - 16384) >> 7;
        row = 128 + rb;
        srcp = Bw + (size_t)(n0 + rb) * K + k0 + (cb >> 1);
      }
      int sw = row * 128 + (cb ^ ((row & 7) << 4));
      *(u16x8*)(sAB + sw) = *(const u16x8*)srcp;
    }
    __syncthreads();
#pragma unroll
    for (int ks = 0; ks < 2; ++ks) {
      int kb = ks * 64 + lg * 16;
      short8 a[4], bbf[2];
#pragma unroll
      for (int mt = 0; mt < 4; ++mt) {
        int rr = wm + mt * 16 + l15;
        a[mt] = *(const short8*)(sAB + rr * 128 + (kb ^ ((rr & 7) << 4)));
      }
#pragma unroll
      for (int nt = 0; nt < 2; ++nt) {
        int rr = 128 + wn + nt * 16 + l15;
        bbf[nt] = *(const short8*)(sAB + rr * 128 + (kb ^ ((rr & 7) << 4)));
      }
#pragma unroll
      for (int mt = 0; mt < 4; ++mt)
#pragma unroll
        for (int nt = 0; nt < 2; ++nt)
          acc[mt][nt] = __builtin_amdgcn_mfma_f32_16x16x32_bf16(a[mt], bbf[nt], acc[mt][nt], 0, 0, 0);
    }
  }
#pragma unroll
  for (int mt = 0; mt < 4; ++mt)
#pragma unroll
    for (int nt = 0; nt < 2; ++nt)
#pragma unroll
      for (int r = 0; r < 4; ++r) {
        int row = m0 + wm + mt * 16 + lg * 4 + r;
        int col = n0 + wn + nt * 16 + l15;
        float v = acc[mt][nt][r];
        if (EPI == 0) {
          v = v > 0.f ? v : 0.f;
          Cb[(size_t)row * N + col] = f2bf(v);
        } else {
          Cf[(size_t)row * N + col] = 1.f / (1.f + __expf(-v));
        }
      }
}

// ---------------- LayerNorm ----------------
__global__ void ln_kernel(float* __restrict__ lr, const float* __restrict__ g,
                          const float* __restrict__ bta) {
  int row = blockIdx.x;
  float* p = lr + (size_t)row * 1024;
  int tid = threadIdx.x;
  float v[4];
#pragma unroll
  for (int i = 0; i < 4; ++i) v[i] = p[tid + 256 * i];
  __shared__ float red[256];
  red[tid] = v[0] + v[1] + v[2] + v[3];
  __syncthreads();
  for (int off = 128; off > 0; off >>= 1) {
    if (tid < off) red[tid] += red[tid + off];
    __syncthreads();
  }
  float mu = red[0] * (1.f / 1024.f);
  __syncthreads();
  float sq = 0.f;
#pragma unroll
  for (int i = 0; i < 4; ++i) { float d = v[i] - mu; sq += d * d; }
  red[tid] = sq;
  __syncthreads();
  for (int off = 128; off > 0; off >>= 1) {
    if (tid < off) red[tid] += red[tid + off];
    __syncthreads();
  }
  float rs = rsqrtf(red[0] * (1.f / 1024.f) + 1e-6f);
#pragma unroll
  for (int i = 0; i < 4; ++i) {
    int idx = tid + 256 * i;
    p[idx] = (v[i] - mu) * rs * g[idx] + bta[idx];
  }
}

// ---------------- x_t = x_t * lr + pe ----------------
__global__ void combine_kernel(float* __restrict__ xt, const float* __restrict__ lr) {
  size_t idx = (size_t)blockIdx.x * 256 + threadIdx.x;
  int l = (int)(idx & 1023);
  int c = (int)((idx >> 10) & 127);
  int t = c & 63;
  float inv = __expf(-0.14619589f * (float)t);
  float st = (float)l * inv;
  float pe = (c < 64) ? sinf(st) : cosf(st);
  xt[idx] = xt[idx] * lr[idx] + pe;
}

// ================= fused CIL node: all 4 ccbs in one block =================
constexpr size_t SEGc = (size_t)NB * NC;
constexpr int TT = 32;

// conv over 5 taps: acc[mt][nt] (co = wv*32+mt*16+..., row = nt*16+l15) from
// bf16 LDS tile (256B rows, 16B-granule XOR swizzle) and packed weights [k][co][ci].
template <int NT>
__device__ __forceinline__ void conv_mfma(const char* Sb, const u16* W, const float* Bp,
                                          int wv, int lg, int l15, f32x4 (&acc)[2][NT]) {
#pragma unroll
  for (int mt = 0; mt < 2; ++mt) {
    const f32x4 bv = *(const f32x4*)(Bp + wv * 32 + mt * 16 + lg * 4);
#pragma unroll
    for (int nt = 0; nt < NT; ++nt) acc[mt][nt] = bv;
  }
  for (int k = 0; k < 5; ++k) {
#pragma unroll
    for (int cig = 0; cig < 4; ++cig) {
      int ci0 = cig * 32 + lg * 8;
      short8 a[2], bb[NT];
#pragma unroll
      for (int mt = 0; mt < 2; ++mt) {
        int co = wv * 32 + mt * 16 + l15;
        a[mt] = *(const short8*)(W + ((size_t)(k * 128 + co) * 128 + ci0));
      }
      int cbyte = 2 * ci0;
#pragma unroll
      for (int nt = 0; nt < NT; ++nt) {
        int i = nt * 16 + l15 + k;
        bb[nt] = *(const short8*)(Sb + i * 256 + (cbyte ^ ((i & 15) << 4)));
      }
#pragma unroll
      for (int mt = 0; mt < 2; ++mt)
#pragma unroll
        for (int nt = 0; nt < NT; ++nt)
          acc[mt][nt] = __builtin_amdgcn_mfma_f32_16x16x32_bf16(a[mt], bb[nt], acc[mt][nt], 0, 0, 0);
    }
  }
}

template <int NT>
__device__ __forceinline__ void write_mid_leaky(char* D, f32x4 (&acc)[2][NT],
                                                int wv, int lg, int l15) {
#pragma unroll
  for (int mt = 0; mt < 2; ++mt)
#pragma unroll
    for (int nt = 0; nt < NT; ++nt) {
      int j = nt * 16 + l15;
      int co0 = wv * 32 + mt * 16 + lg * 4;
      u16x4 m;
#pragma unroll
      for (int r = 0; r < 4; ++r) {
        float v = acc[mt][nt][r];
        v = v > 0.f ? v : 0.01f * v;
        m[r] = f2bf(v);
      }
      *(u16x4*)(D + j * 256 + ((2 * co0) ^ ((j & 15) << 4))) = m;
    }
}

// LDS: R_SE[52] R_SO[52] R_M[52] bf16 tiles (13312B each), XEF/XOF fp32 [40][130]
__global__ __launch_bounds__(256, 2) void fused_cil(const float* __restrict__ src,
                                                    float* __restrict__ dst,
                                                    const u16* __restrict__ wp1,
                                                    const u16* __restrict__ wp2,
                                                    const float* __restrict__ b1,
                                                    const float* __restrict__ b2,
                                                    int d, int Tn) {
  __shared__ __align__(16) char sm[81536];
  char* R_SE = sm;                       // parent even bf16 -> xot bf16
  char* R_SO = sm + 13312;               // parent odd bf16 -> mids
  char* R_M  = sm + 26624;               // mid1 -> xet bf16
  float* XEF = (float*)(sm + 39936);     // parent even fp32 -> xet fp32 (in place)
  float* XOF = (float*)(sm + 60736);     // parent odd fp32 -> xot fp32

  int b = blockIdx.x;
  int t0 = blockIdx.y * TT;
  int p = blockIdx.z;
  // preorder node index of (depth d, BFS pos p)
  int node = 0;
  for (int i2 = d - 1; i2 >= 0; --i2) {
    int bit = (p >> i2) & 1;
    int dd = d - 1 - i2;
    node += 1 + bit * ((1 << (3 - dd)) - 1);
  }
  const size_t WSZ = 5 * 128 * 128;
  const u16* W1a = wp1 + (size_t)(node * 4 + 0) * WSZ;
  const u16* W1b = wp1 + (size_t)(node * 4 + 1) * WSZ;
  const u16* W1c = wp1 + (size_t)(node * 4 + 2) * WSZ;
  const u16* W1d = wp1 + (size_t)(node * 4 + 3) * WSZ;
  const u16* W2a = wp2 + (size_t)(node * 4 + 0) * WSZ;
  const u16* W2b = wp2 + (size_t)(node * 4 + 1) * WSZ;
  const u16* W2c = wp2 + (size_t)(node * 4 + 2) * WSZ;
  const u16* W2d = wp2 + (size_t)(node * 4 + 3) * WSZ;
  const float* B1a = b1 + (size_t)(node * 4 + 0) * 128;
  const float* B1b = b1 + (size_t)(node * 4 + 1) * 128;
  const float* B1c = b1 + (size_t)(node * 4 + 2) * 128;
  const float* B1d = b1 + (size_t)(node * 4 + 3) * 128;
  const float* B2a = b2 + (size_t)(node * 4 + 0) * 128;
  const float* B2b = b2 + (size_t)(node * 4 + 1) * 128;
  const float* B2c = b2 + (size_t)(node * 4 + 2) * 128;
  const float* B2d = b2 + (size_t)(node * 4 + 3) * 128;

  int tid = threadIdx.x;
  int TW = 2 * Tn;
  const float* inb = src + ((size_t)p * SEGc + (size_t)b * NC) * TW;

  // ---- stage parent: 52 rows (tau = t0-8+i, clamped), both parities ----
  {
    int i = tid & 63;
    int wq = tid >> 6;
    if (i < 52) {
      int t = t0 - 8 + i;
      t = t < 0 ? 0 : (t >= Tn ? Tn - 1 : t);
      bool fr = (i >= 4) && (i < 44);
      const float* rowp = inb + 2 * t;
      int sw0 = (i & 15) << 4;
#pragma unroll
      for (int pp = 0; pp < 16; ++pp) {
        int pr = wq * 16 + pp;
        float2 v0 = *(const float2*)(rowp + (size_t)(2 * pr) * TW);
        float2 v1 = *(const float2*)(rowp + (size_t)(2 * pr + 1) * TW);
        unsigned pe = (unsigned)f2bf(v0.x) | ((unsigned)f2bf(v1.x) << 16);
        unsigned po = (unsigned)f2bf(v0.y) | ((unsigned)f2bf(v1.y) << 16);
        int sw = (4 * pr) ^ sw0;
        *(unsigned*)(R_SE + i * 256 + sw) = pe;
        *(unsigned*)(R_SO + i * 256 + sw) = po;
        if (fr) {
          *(float2*)(XEF + (i - 4) * 130 + 2 * pr) = make_float2(v0.x, v1.x);
          *(float2*)(XOF + (i - 4) * 130 + 2 * pr) = make_float2(v0.y, v1.y);
        }
      }
    }
  }
  __syncthreads();  // B1

  int lane = tid & 63, wv = tid >> 6;
  int lg = lane >> 4, l15 = lane & 15;
  int co_base = wv * 32 + lg * 4;

  // ---- ccb0: conv1 on xo ----
  {
    f32x4 acc1[2][3];
    conv_mfma<3>(R_SO, W1a, B1a, wv, lg, l15, acc1);
    write_mid_leaky<3>(R_M, acc1, wv, lg, l15);
  }
  __syncthreads();  // B2

  // ---- ccb0: conv2 + xet = xe * exp(tanh) ----
  u16x4 sxet[2][3];
  {
    f32x4 acc2[2][3];
    conv_mfma<3>(R_M, W2a, B2a, wv, lg, l15, acc2);
#pragma unroll
    for (int mt = 0; mt < 2; ++mt)
#pragma unroll
      for (int nt = 0; nt < 3; ++nt) {
        int jx = nt * 16 + l15;
        if (jx < 40) {
          int co0 = co_base + mt * 16;
          float* rowf = XEF + jx * 130 + co0;
          float2 a01 = *(float2*)rowf;
          float2 a23 = *(float2*)(rowf + 2);
          float xv[4] = {a01.x, a01.y, a23.x, a23.y};
          u16x4 mb;
#pragma unroll
          for (int r = 0; r < 4; ++r) {
            float res = xv[r] * __expf(ftanh(acc2[mt][nt][r]));
            rowf[r] = res;
            mb[r] = f2bf(res);
          }
          sxet[mt][nt] = mb;
        }
      }
  }
  __syncthreads();  // B3 (conv2a reads of R_M done; XEF updates visible later)

  // xet bf16 -> R_M
#pragma unroll
  for (int mt = 0; mt < 2; ++mt)
#pragma unroll
    for (int nt = 0; nt < 3; ++nt) {
      int jx = nt * 16 + l15;
      if (jx < 40) {
        int co0 = co_base + mt * 16;
        *(u16x4*)(R_M + jx * 256 + ((2 * co0) ^ ((jx & 15) << 4))) = sxet[mt][nt];
      }
    }

  // ---- ccb1: conv1 on xe ----
  {
    f32x4 acc1[2][3];
    conv_mfma<3>(R_SE, W1b, B1b, wv, lg, l15, acc1);
    write_mid_leaky<3>(R_SO, acc1, wv, lg, l15);
  }
  __syncthreads();  // B4

  // ---- ccb1: conv2 + xot = xo * exp(tanh) ----
  u16x4 sxot[2][3];
  {
    f32x4 acc2[2][3];
    conv_mfma<3>(R_SO, W2b, B2b, wv, lg, l15, acc2);
#pragma unroll
    for (int mt = 0; mt < 2; ++mt)
#pragma unroll
      for (int nt = 0; nt < 3; ++nt) {
        int jx = nt * 16 + l15;
        if (jx < 40) {
          int co0 = co_base + mt * 16;
          float* rowf = XOF + jx * 130 + co0;
          float2 a01 = *(float2*)rowf;
          float2 a23 = *(float2*)(rowf + 2);
          float xv[4] = {a01.x, a01.y, a23.x, a23.y};
          u16x4 mb;
#pragma unroll
          for (int r = 0; r < 4; ++r) {
            float res = xv[r] * __expf(ftanh(acc2[mt][nt][r]));
            rowf[r] = res;
            mb[r] = f2bf(res);
          }
          sxot[mt][nt] = mb;
        }
      }
  }
  __syncthreads();  // B5 (conv2b reads of R_SO done)

  // xot bf16 -> R_SE
#pragma unroll
  for (int mt = 0; mt < 2; ++mt)
#pragma unroll
    for (int nt = 0; nt < 3; ++nt) {
      int jx = nt * 16 + l15;
      if (jx < 40) {
        int co0 = co_base + mt * 16;
        *(u16x4*)(R_SE + jx * 256 + ((2 * co0) ^ ((jx & 15) << 4))) = sxot[mt][nt];
      }
    }

  // ---- boundary fixup: edge-pad xet/xot bf16 tiles ----
  if (t0 == 0 || t0 == Tn - TT) {
    __syncthreads();
    int rs = (t0 == 0) ? 4 : 35;
    int rd0 = (t0 == 0) ? 0 : 36;
    for (int w = tid; w < 512; w += 256) {
      int buf = w >> 8;
      int rr = (w >> 6) & 3;
      int c4 = (w & 63) * 4;
      char* Bse = buf ? R_M : R_SE;
      int rdst = rd0 + rr;
      *(unsigned*)(Bse + rdst * 256 + (c4 ^ ((rdst & 15) << 4))) =
          *(unsigned*)(Bse + rs * 256 + (c4 ^ ((rs & 15) << 4)));
    }
  }
  __syncthreads();  // B6

  // ---- ccb2: conv1 on xot ----
  {
    f32x4 acc1[2][3];
    conv_mfma<3>(R_SE, W1c, B1c, wv, lg, l15, acc1);
    write_mid_leaky<3>(R_SO, acc1, wv, lg, l15);
  }
  __syncthreads();  // B7

  float* outEb = dst + ((size_t)(2 * p) * SEGc + (size_t)b * NC) * Tn;
  float* outOb = dst + ((size_t)(2 * p + 1) * SEGc + (size_t)b * NC) * Tn;

  // ---- ccb2: conv2 -> e = xet + tanh ----
  {
    f32x4 acc2[2][2];
    conv_mfma<2>(R_SO, W2c, B2c, wv, lg, l15, acc2);
#pragma unroll
    for (int mt = 0; mt < 2; ++mt)
#pragma unroll
      for (int nt = 0; nt < 2; ++nt) {
        int tl = nt * 16 + l15;
        int co0 = co_base + mt * 16;
        const float* xrow = XEF + (tl + 4) * 130 + co0;
#pragma unroll
        for (int r = 0; r < 4; ++r) {
          float res = xrow[r] + ftanh(acc2[mt][nt][r]);
          outEb[(size_t)(co0 + r) * Tn + t0 + tl] = res;
        }
      }
  }
  // ---- ccb3: conv1 on xet (R_M) ----
  f32x4 acc1d[2][3];
  conv_mfma<3>(R_M, W1d, B1d, wv, lg, l15, acc1d);
  __syncthreads();  // B8 (conv2c reads of R_SO done)
  write_mid_leaky<3>(R_SO, acc1d, wv, lg, l15);
  __syncthreads();  // B9

  // ---- ccb3: conv2 -> o = xot - tanh ----
  {
    f32x4 acc2[2][2];
    conv_mfma<2>(R_SO, W2d, B2d, wv, lg, l15, acc2);
#pragma unroll
    for (int mt = 0; mt < 2; ++mt)
#pragma unroll
      for (int nt = 0; nt < 2; ++nt) {
        int tl = nt * 16 + l15;
        int co0 = co_base + mt * 16;
        const float* xrow = XOF + (tl + 4) * 130 + co0;
#pragma unroll
        for (int r = 0; r < 4; ++r) {
          float res = xrow[r] - ftanh(acc2[mt][nt][r]);
          outOb[(size_t)(co0 + r) * Tn + t0 + tl] = res;
        }
      }
  }
}

// ---------------- final projection + denorm (gathers leaf layout) ----------------
__global__ void final_kernel(const float* __restrict__ dect, const float* __restrict__ xt,
                             const float* __restrict__ projw, const float* __restrict__ means,
                             const float* __restrict__ stdev, float* __restrict__ out) {
  int b = blockIdx.x, p = blockIdx.y;
  int tid = threadIdx.x;
  const float* w = projw + (size_t)(1024 + p) * 1024;
  const float* x0 = xt + (size_t)b * NC * NL;
  float a[3] = {0.f, 0.f, 0.f};
  for (int l = tid; l < 1024; l += 256) {
    float wv = w[l];
    int rl = l & 7;
    int pb = ((rl & 1) << 2) | (rl & 2) | (rl >> 2);
    int br = (l >> 3) & 1;
    int t = l >> 4;
    const float* dl = dect + ((size_t)(2 * pb + br) * NB + b) * NC * 64 + t;
#pragma unroll
    for (int cc = 0; cc < 3; ++cc)
      a[cc] += wv * (dl[(size_t)cc * 64] + x0[(size_t)cc * NL + l]);
  }
  __shared__ float red[3][256];
  for (int cc = 0; cc < 3; ++cc) red[cc][tid] = a[cc];
  __syncthreads();
  for (int off = 128; off > 0; off >>= 1) {
    if (tid < off) {
      red[0][tid] += red[0][tid + off];
      red[1][tid] += red[1][tid + off];
      red[2][tid] += red[2][tid + off];
    }
    __syncthreads();
  }
  if (tid < 3) {
    out[((size_t)b * NP + p) * 3 + tid] = red[tid][0] * stdev[b * NC + tid] + means[b * NC + tid];
  }
}

}  // namespace

extern "C" void kernel_launch(void* const* d_in, const int* in_sizes, int n_in,
                              void* d_out, int out_size, void* d_ws, size_t ws_size,
                              hipStream_t stream) {
  (void)in_sizes; (void)n_in; (void)out_size; (void)ws_size;
  const float* x_enc = (const float*)d_in[0];
  const float* mask  = (const float*)d_in[1];
  const float* fc1_w = (const float*)d_in[2];
  const float* fc2_w = (const float*)d_in[3];
  const float* ln_g  = (const float*)d_in[4];
  const float* ln_b  = (const float*)d_in[5];
  const float* w1    = (const float*)d_in[6];
  const float* b1    = (const float*)d_in[7];
  const float* w2    = (const float*)d_in[8];
  const float* b2    = (const float*)d_in[9];
  const float* projw = (const float*)d_in[10];
  float* out = (float*)d_out;
  float* ws = (float*)d_ws;

  float* means = ws + 0;          // 4096
  float* stdev = ws + 4096;       // 4096
  float* x_t   = ws + 139264;     // 4,194,304  (B,C,L) fp32, depth-0 parent
  float* freq  = ws + 4333568;    // 4,194,304  lr fp32 -> depth-2 out
  float* IN1   = ws + 8527872;    // 4,194,304  hid_bf -> depth-0 out -> leaf out (dect)
  float* IN2   = ws + 12722176;   // 4,194,304  fc w bf16 -> depth-1 out
  float* xetr  = ws + 16916480;   // freq_bf (bf16)
  float* wp1f  = ws + 21110784;   // stats partials -> packed conv w1 bf16
  float* wp2f  = ws + 23568384;   // packed conv w2 bf16
  float* dect = IN1;
  float* stats_part = wp1f;
  u16* freq_bf = (u16*)xetr;
  u16* hid_bf  = (u16*)IN1;
  u16* fc1w_bf = (u16*)IN2;
  u16* fc2w_bf = (u16*)(IN2 + 1048576);
  u16* wp1 = (u16*)wp1f;
  u16* wp2 = (u16*)wp2f;

  stats1<<<dim3(NB, 16), 256, 0, stream>>>(x_enc, mask, stats_part);
  stats2<<<NB, 128, 0, stream>>>(stats_part, means, stdev);
  norm_transpose<<<dim3(NB, NL / 32, NC / 32), dim3(32, 8), 0, stream>>>(x_enc, mask, means, stdev, x_t);
  haar_kernel<<<NB * NC, 256, 0, stream>>>(x_t, freq_bf);

  cvt_bf16<<<2048, 256, 0, stream>>>(fc1_w, fc1w_bf, 524288);
  cvt_bf16<<<2048, 256, 0, stream>>>(fc2_w, fc2w_bf, 524288);
  pack_w<<<3840, 256, 0, stream>>>(w1, wp1);
  pack_w<<<3840, 256, 0, stream>>>(w2, wp2);

  gemm_mfma<0><<<dim3(32, 32), 256, 0, stream>>>(freq_bf, fc1w_bf, hid_bf, nullptr, 4096, 2048, 1024);
  gemm_mfma<1><<<dim3(16, 32), 256, 0, stream>>>(hid_bf, fc2w_bf, nullptr, freq, 4096, 1024, 2048);

  ln_kernel<<<4096, 256, 0, stream>>>(freq, ln_g, ln_b);
  combine_kernel<<<(NB * NC * NL) / 256, 256, 0, stream>>>(x_t, freq);

  // tree: 4 fused launches; depth-buffers: x_t -> IN1 -> IN2 -> freq -> IN1(dect)
  float* dbuf[5] = {x_t, IN1, IN2, freq, IN1};
  for (int d = 0; d < 4; ++d) {
    int Tn = 512 >> d;
    dim3 grid(NB, Tn / TT, 1 << d);
    fused_cil<<<grid, 256, 0, stream>>>(dbuf[d], dbuf[d + 1], wp1, wp2, b1, b2, d, Tn);
  }

  final_kernel<<<dim3(NB, NP), 256, 0, stream>>>(dect, x_t, projw, means, stdev, out);
}